// Round 1
// 227.773 us; speedup vs baseline: 1.0965x; 1.0965x over previous
//
#include <hip/hip_runtime.h>
#include <hip/hip_bf16.h>
#include <type_traits>

typedef __hip_bfloat16 bf16;
typedef __attribute__((ext_vector_type(8))) short bf16x8;
typedef __attribute__((ext_vector_type(4))) float f32x4;

#define N_LOC 4096

__device__ __forceinline__ bf16 to_bf16(float f) { return __float2bfloat16(f); }

// async global->LDS DMA, 16B per lane; LDS dest = wave-uniform base + lane*16
__device__ __forceinline__ void dma16(const bf16* g, bf16* l) {
  __builtin_amdgcn_global_load_lds((const __attribute__((address_space(1))) unsigned int*)g,
                                   (__attribute__((address_space(3))) unsigned int*)l, 16, 0, 0);
}

// ---------------- fused conversion f32 -> bf16 for Q,K,V,Wo ----------------
__global__ __launch_bounds__(256) void convert_all(const float* __restrict__ Q,
                                                   const float* __restrict__ K,
                                                   const float* __restrict__ V,
                                                   const float* __restrict__ Wo,
                                                   bf16* __restrict__ Qb, bf16* __restrict__ Kb,
                                                   bf16* __restrict__ Vb, bf16* __restrict__ Wob) {
  long i = ((long)blockIdx.x * 256 + threadIdx.x) * 8;
  const float* src;
  bf16* dst;
  long off;
  if (i < 2097152)      { src = Q;  dst = Qb;  off = i; }
  else if (i < 4194304) { src = K;  dst = Kb;  off = i - 2097152; }
  else if (i < 6291456) { src = V;  dst = Vb;  off = i - 4194304; }
  else                  { src = Wo; dst = Wob; off = i - 6291456; }
  float4 a = *(const float4*)&src[off];
  float4 b = *(const float4*)&src[off + 4];
  union { bf16 h[8]; bf16x8 v; } u;
  u.h[0] = to_bf16(a.x); u.h[1] = to_bf16(a.y); u.h[2] = to_bf16(a.z); u.h[3] = to_bf16(a.w);
  u.h[4] = to_bf16(b.x); u.h[5] = to_bf16(b.y); u.h[6] = to_bf16(b.z); u.h[7] = to_bf16(b.w);
  *(bf16x8*)&dst[off] = u.v;
}

// ---------------- W pack: [H][512][DH] -> Bt [H*DH][512], LDS-tiled transpose ----------------
__global__ __launch_bounds__(256) void pack_wt(const float* __restrict__ Wq,
                                               const float* __restrict__ Wk,
                                               const float* __restrict__ Wv,
                                               bf16* __restrict__ oq, bf16* __restrict__ ok,
                                               bf16* __restrict__ ov) {
  int z = blockIdx.z;
  const float* W = (z == 0) ? Wq : (z == 1) ? Wk : Wv;
  bf16* out = (z == 0) ? oq : (z == 1) ? ok : ov;
  int DH = (z == 2) ? 256 : 128;
  int nt = DH >> 6;
  int y = blockIdx.y;
  if (y >= 4 * nt) return;
  int h = y / nt, tt = y - h * nt;
  int d0 = blockIdx.x * 64, t0 = tt * 64;
  __shared__ float tile[64][65];
  for (int i = threadIdx.x; i < 4096; i += 256) {
    int r = i >> 6, c = i & 63;
    tile[r][c] = W[((size_t)h * 512 + d0 + r) * DH + t0 + c];
  }
  __syncthreads();
  for (int i = threadIdx.x; i < 4096; i += 256) {
    int t = i >> 6, d = i & 63;
    out[((size_t)(h * DH + t0 + t)) * 512 + d0 + d] = to_bf16(tile[d][t]);
  }
}

// ---------------- 128x128 GEMM body: C[M][N] = A[M][K] * Bt[N][K]^T ----------------
// m97 structure: global_load_lds staging with pre-swizzled source (granule G of row r
// stored at position G^(r&7) -> conflict-free ds_read_b128 fragment reads), BK=64,
// 4 waves each owning a 64x64 output (4x4 frags of 16x16x32), 2 barriers per K-step.
template <typename OutT>
__device__ __forceinline__ void gemm128_body(const bf16* __restrict__ A,
                                             const bf16* __restrict__ Bt,
                                             OutT* __restrict__ C, int M, int N, int K,
                                             int m0, int n0, bf16* As, bf16* Bs) {
  int tid = threadIdx.x;
  int lane = tid & 63, w = tid >> 6;
  int quad = lane >> 4, l16 = lane & 15;
  int wm = (w >> 1) * 64, wn = (w & 1) * 64;
  int srow = lane >> 3;            // row-within-8-group staged by this lane
  int sG = (lane & 7) ^ srow;      // source granule for stored position lane&7

  f32x4 acc[4][4] = {};
  for (int k0 = 0; k0 < K; k0 += 64) {
#pragma unroll
    for (int j = 0; j < 4; j++) {
      int rg = 4 * j + w;          // 8-row group 0..15
      dma16(&A[(long)(m0 + rg * 8 + srow) * K + k0 + sG * 8], &As[rg * 512]);
      dma16(&Bt[(long)(n0 + rg * 8 + srow) * K + k0 + sG * 8], &Bs[rg * 512]);
    }
    __syncthreads();
#pragma unroll
    for (int kk = 0; kk < 2; kk++) {
      bf16x8 af[4], bfr[4];
#pragma unroll
      for (int i = 0; i < 4; i++) {
        int r = wm + i * 16 + l16;
        af[i] = *(const bf16x8*)&As[r * 64 + (((kk * 4 + quad) ^ r) & 7) * 8];
      }
#pragma unroll
      for (int j = 0; j < 4; j++) {
        int r = wn + j * 16 + l16;
        bfr[j] = *(const bf16x8*)&Bs[r * 64 + (((kk * 4 + quad) ^ r) & 7) * 8];
      }
#pragma unroll
      for (int i = 0; i < 4; i++)
#pragma unroll
        for (int j = 0; j < 4; j++)
          acc[i][j] = __builtin_amdgcn_mfma_f32_16x16x32_bf16(af[i], bfr[j], acc[i][j], 0, 0, 0);
    }
    __syncthreads();
  }
#pragma unroll
  for (int i = 0; i < 4; i++)
#pragma unroll
    for (int j = 0; j < 4; j++)
#pragma unroll
      for (int r = 0; r < 4; r++) {
        long row = m0 + wm + i * 16 + quad * 4 + r;
        long col = n0 + wn + j * 16 + l16;
        if constexpr (std::is_same<OutT, bf16>::value)
          C[row * N + col] = to_bf16(acc[i][j][r]);
        else
          C[row * N + col] = acc[i][j][r];
      }
}

// merged q/k/v projections: z picks contiguous slices of inputs/weights/outputs
__global__ __launch_bounds__(256) void proj_gemm(const bf16* __restrict__ QKVb,
                                                 const bf16* __restrict__ Wt,
                                                 bf16* __restrict__ Cout) {
  int z = blockIdx.z;
  int N = (z == 2) ? 1024 : 512;
  if ((int)(blockIdx.y * 128) >= N) return;   // block-uniform early-out
  __shared__ __align__(16) bf16 As[128 * 64];
  __shared__ __align__(16) bf16 Bs[128 * 64];
  const bf16* A = QKVb + (size_t)z * 2097152;
  const bf16* Bt = Wt + ((z == 2) ? (size_t)524288 : (size_t)z * 262144);
  bf16* C = Cout + (size_t)z * 2097152;
  gemm128_body<bf16>(A, Bt, C, 4096, N, 512, blockIdx.x * 128, blockIdx.y * 128, As, Bs);
}

__global__ __launch_bounds__(256) void out_gemm(const bf16* __restrict__ xin,
                                                const bf16* __restrict__ Wob,
                                                float* __restrict__ outp) {
  __shared__ __align__(16) bf16 As[128 * 64];
  __shared__ __align__(16) bf16 Bs[128 * 64];
  gemm128_body<float>(xin, Wob, outp, 4096, 512, 1024, blockIdx.x * 128, blockIdx.y * 128, As, Bs);
}

// ---------------- transpose (R x C) -> (C x R): per-thread 8x8 register transpose ----------------
// scattered 16B loads (L2/L3-resident), fully coalesced 16B stores, no LDS.
__global__ __launch_bounds__(256) void transpose_bf16(const bf16* __restrict__ in,
                                                      bf16* __restrict__ out, int R, int Cc) {
  long T = (long)blockIdx.x * 256 + threadIdx.x;
  long nrb = (long)(R >> 3);
  long rb = T % nrb;                 // lane-contiguous -> coalesced stores
  long cb = T / nrb;
  union { bf16 h[8]; bf16x8 v; } a[8], b[8];
#pragma unroll
  for (int i = 0; i < 8; i++) a[i].v = *(const bf16x8*)&in[(rb * 8 + i) * Cc + cb * 8];
#pragma unroll
  for (int j = 0; j < 8; j++) {
#pragma unroll
    for (int i = 0; i < 8; i++) b[j].h[i] = a[i].h[j];
    *(bf16x8*)&out[(cb * 8 + j) * R + rb * 8] = b[j].v;
  }
}

// ---------------- fused attention ----------------
// qb,kb: [N][512]; vT: [1024][N]; x: [N][1024]
// 512 threads = 8 waves; 64 queries/block; 64-key tiles.
// NEW: kt/vt double-buffered; raw s_barrier + counted s_waitcnt vmcnt(6) so the next
// tile's 6 DMA instructions stay in flight across all three barriers (no vmcnt(0)
// drain in the loop). Every raw barrier is fenced with asm memory clobbers so the
// compiler cannot migrate LDS ops across it (rule #18/#21 discipline).
__global__ __launch_bounds__(512, 2) void attn(const bf16* __restrict__ qb,
                                               const bf16* __restrict__ kb,
                                               const bf16* __restrict__ vT,
                                               bf16* __restrict__ x) {
  __shared__ __align__(16) bf16 kt[2][64 * 128];   // [key][dk] swizzled, 2x16 KB
  __shared__ __align__(16) bf16 vt[2][256 * 64];   // [dv][key] swizzled, 2x32 KB
  __shared__ __align__(16) bf16 pt[64 * 72];       // [q][key], padded
  __shared__ float Lrow[64];

  const int head = blockIdx.x & 3;
  const int q0 = (blockIdx.x >> 2) * 64;
  const int tid = threadIdx.x;
  const int lane = tid & 63, w = tid >> 6;
  const int quad = lane >> 4, l16 = lane & 15;
  const int cd = w & 3;   // S: key-col tile; PV: dv group
  const int g = w >> 2;   // q half

  // all-ones B-fragment: B[n][k] = (n==0) -> D[q][0] = sum_k P[q][k]
  bf16x8 onesf;
  {
    union { bf16 h[8]; bf16x8 v; } u;
    bf16 one = to_bf16(1.0f), zero = to_bf16(0.0f);
#pragma unroll
    for (int j = 0; j < 8; j++) u.h[j] = (l16 == 0) ? one : zero;
    onesf = u.v;
  }

  // preload q fragments (A-layout: m=l16, k=quad*8+j)
  bf16x8 qf[2][4];
#pragma unroll
  for (int i = 0; i < 2; i++) {
    const bf16* qrow = &qb[(size_t)(q0 + g * 32 + i * 16 + l16) * 512 + head * 128];
#pragma unroll
    for (int kk = 0; kk < 4; kk++) qf[i][kk] = *(const bf16x8*)&qrow[kk * 32 + quad * 8];
  }

  f32x4 oacc[2][4] = {};
  f32x4 oL[2] = {};
  const float scale = 1.0f / 64.0f;  // 1/sqrt(4096)

  // stage one key-tile into buffer b: 6 DMA instrs per wave (2 kt + 4 vt)
  auto stage = [&](int b, int key0) {
#pragma unroll
    for (int t2 = 0; t2 < 2; t2++) {
      int j = 2 * w + t2;
      int r = 4 * j + (lane >> 4);            // key row 0..63
      int p = lane & 15;                      // stored granule position
      int G = (p & 8) | ((p ^ r) & 7);        // source granule (inverse swizzle)
      dma16(&kb[(size_t)(key0 + r) * 512 + head * 128 + G * 8], &kt[b][j * 512]);
    }
#pragma unroll
    for (int t2 = 0; t2 < 4; t2++) {
      int j = 4 * w + t2;
      int r = 8 * j + (lane >> 3);            // dv row 0..255
      int p = lane & 7;
      int G = (p ^ r) & 7;
      dma16(&vT[(size_t)(head * 256 + r) * 4096 + key0 + G * 8], &vt[b][j * 512]);
    }
  };

  stage(0, 0);
  asm volatile("" ::: "memory");   // pin prologue DMA (+qf loads) before loop's stage
  int cur = 0;

  for (int t = 0; t < 64; ++t) {
    // ---- issue next tile's DMA, then wait (counted) for current tile ----
    if (t < 63) {
      stage(cur ^ 1, (t + 1) * 64);
      asm volatile("s_waitcnt vmcnt(6)" ::: "memory");   // tile t done; t+1's 6 in flight
    } else {
      asm volatile("s_waitcnt vmcnt(0)" ::: "memory");
    }
    __builtin_amdgcn_s_barrier();          // barrier A: all waves' tile-t DMA landed
    asm volatile("" ::: "memory");

    // ---- S = q @ k^T : this wave: q rows g*32..+31, key col cd ----
    const bf16* ktc = kt[cur];
    f32x4 sacc[2] = {};
#pragma unroll
    for (int kk = 0; kk < 4; kk++) {
      int R = cd * 16 + l16;
      int G = kk * 4 + quad;
      bf16x8 kf = *(const bf16x8*)&ktc[R * 128 + (((G ^ R) & 7) | (G & 8)) * 8];
      sacc[0] = __builtin_amdgcn_mfma_f32_16x16x32_bf16(qf[0][kk], kf, sacc[0], 0, 0, 0);
      sacc[1] = __builtin_amdgcn_mfma_f32_16x16x32_bf16(qf[1][kk], kf, sacc[1], 0, 0, 0);
    }
#pragma unroll
    for (int i = 0; i < 2; i++)
#pragma unroll
      for (int r = 0; r < 4; r++)
        pt[(g * 32 + i * 16 + quad * 4 + r) * 72 + cd * 16 + l16] =
            to_bf16(__expf(sacc[i][r] * scale));
    asm volatile("s_waitcnt lgkmcnt(0)" ::: "memory");   // own pt writes visible
    __builtin_amdgcn_s_barrier();          // barrier B: pt ready
    asm volatile("" ::: "memory");

    // ---- O += P @ v : this wave: q rows g*32..+31, dv cols cd*64..+63 ----
    const bf16* vtc = vt[cur];
#pragma unroll
    for (int kk = 0; kk < 2; kk++) {
      bf16x8 pf[2];
#pragma unroll
      for (int i = 0; i < 2; i++)
        pf[i] = *(const bf16x8*)&pt[(g * 32 + i * 16 + l16) * 72 + kk * 32 + quad * 8];
#pragma unroll
      for (int c = 0; c < 4; c++) {
        int R = cd * 64 + c * 16 + l16;
        int G = kk * 4 + quad;
        bf16x8 vf = *(const bf16x8*)&vtc[R * 64 + ((G ^ R) & 7) * 8];
#pragma unroll
        for (int i = 0; i < 2; i++)
          oacc[i][c] = __builtin_amdgcn_mfma_f32_16x16x32_bf16(pf[i], vf, oacc[i][c], 0, 0, 0);
      }
      if (cd == 3) {  // wave-uniform: L column
#pragma unroll
        for (int i = 0; i < 2; i++)
          oL[i] = __builtin_amdgcn_mfma_f32_16x16x32_bf16(pf[i], onesf, oL[i], 0, 0, 0);
      }
    }
    asm volatile("" ::: "memory");
    __builtin_amdgcn_s_barrier();          // barrier C: buf cur free for reuse
    asm volatile("" ::: "memory");
    cur ^= 1;
  }

  // L at lanes l16==0 of cd==3 waves (C-layout col 0)
  if (cd == 3 && l16 == 0) {
#pragma unroll
    for (int i = 0; i < 2; i++)
#pragma unroll
      for (int r = 0; r < 4; r++) Lrow[g * 32 + i * 16 + quad * 4 + r] = oL[i][r];
  }
  __syncthreads();

  // normalize + write x[n][head*256 + dv]
#pragma unroll
  for (int i = 0; i < 2; i++)
#pragma unroll
    for (int c = 0; c < 4; c++)
#pragma unroll
      for (int r = 0; r < 4; r++) {
        int row = g * 32 + i * 16 + quad * 4 + r;
        float v = oacc[i][c][r] / Lrow[row];
        x[(size_t)(q0 + row) * 1024 + head * 256 + cd * 64 + c * 16 + l16] = to_bf16(v);
      }
}

// ---------------- launch ----------------
extern "C" void kernel_launch(void* const* d_in, const int* in_sizes, int n_in,
                              void* d_out, int out_size, void* d_ws, size_t ws_size,
                              hipStream_t stream) {
  const float* Q  = (const float*)d_in[0];
  const float* Km = (const float*)d_in[1];
  const float* V  = (const float*)d_in[2];
  const float* Wq = (const float*)d_in[3];
  const float* Wk = (const float*)d_in[4];
  const float* Wv = (const float*)d_in[5];
  const float* Wo = (const float*)d_in[6];
  float* out = (float*)d_out;

  bf16* ws  = (bf16*)d_ws;
  bf16* Qb  = ws;                 // 4096x512   (Qb,Kb,Vb contiguous)
  bf16* Kb  = Qb + 2097152;
  bf16* Vb  = Kb + 2097152;
  bf16* Wqt = Vb + 2097152;       // 512x512  (Wqt,Wkt,Wvt contiguous)
  bf16* Wkt = Wqt + 262144;
  bf16* Wvt = Wkt + 262144;       // 1024x512 (Bt)
  bf16* Wob = Wvt + 524288;       // 512x1024 (Bt = Wo as-is)
  bf16* qb  = Wob + 524288;       // 4096x512   (qb,kb,vb contiguous)
  bf16* kb  = qb + 2097152;
  bf16* vb  = kb + 2097152;       // 4096x1024
  bf16* vT  = vb + 4194304;       // 1024x4096
  bf16* x   = vT + 4194304;       // 4096x1024

  convert_all<<<3328, 256, 0, stream>>>(Q, Km, V, Wo, Qb, Kb, Vb, Wob);
  pack_wt<<<dim3(8, 16, 3), 256, 0, stream>>>(Wq, Wk, Wv, Wqt, Wkt, Wvt);

  // merged q/k/v projections: one 640-useful-block dispatch (z<2 skips y>=4)
  proj_gemm<<<dim3(32, 8, 3), 256, 0, stream>>>(Qb, Wqt, qb);
  transpose_bf16<<<256, 256, 0, stream>>>(vb, vT, 4096, 1024);

  attn<<<256, 512, 0, stream>>>(qb, kb, vT, x);

  out_gemm<<<dim3(32, 4), 256, 0, stream>>>(x, Wob, out);
}

// Round 2
// 220.816 us; speedup vs baseline: 1.1310x; 1.0315x over previous
//
#include <hip/hip_runtime.h>
#include <hip/hip_bf16.h>
#include <type_traits>

typedef __hip_bfloat16 bf16;
typedef __attribute__((ext_vector_type(8))) short bf16x8;
typedef __attribute__((ext_vector_type(4))) float f32x4;

#define N_LOC 4096

__device__ __forceinline__ bf16 to_bf16(float f) { return __float2bfloat16(f); }

// async global->LDS DMA, 16B per lane; LDS dest = wave-uniform base + lane*16
__device__ __forceinline__ void dma16(const bf16* g, bf16* l) {
  __builtin_amdgcn_global_load_lds((const __attribute__((address_space(1))) unsigned int*)g,
                                   (__attribute__((address_space(3))) unsigned int*)l, 16, 0, 0);
}

// ---------------- fused conversion f32 -> bf16 for Q,K,V,Wo ----------------
__global__ __launch_bounds__(256) void convert_all(const float* __restrict__ Q,
                                                   const float* __restrict__ K,
                                                   const float* __restrict__ V,
                                                   const float* __restrict__ Wo,
                                                   bf16* __restrict__ Qb, bf16* __restrict__ Kb,
                                                   bf16* __restrict__ Vb, bf16* __restrict__ Wob) {
  long i = ((long)blockIdx.x * 256 + threadIdx.x) * 8;
  const float* src;
  bf16* dst;
  long off;
  if (i < 2097152)      { src = Q;  dst = Qb;  off = i; }
  else if (i < 4194304) { src = K;  dst = Kb;  off = i - 2097152; }
  else if (i < 6291456) { src = V;  dst = Vb;  off = i - 4194304; }
  else                  { src = Wo; dst = Wob; off = i - 6291456; }
  float4 a = *(const float4*)&src[off];
  float4 b = *(const float4*)&src[off + 4];
  union { bf16 h[8]; bf16x8 v; } u;
  u.h[0] = to_bf16(a.x); u.h[1] = to_bf16(a.y); u.h[2] = to_bf16(a.z); u.h[3] = to_bf16(a.w);
  u.h[4] = to_bf16(b.x); u.h[5] = to_bf16(b.y); u.h[6] = to_bf16(b.z); u.h[7] = to_bf16(b.w);
  *(bf16x8*)&dst[off] = u.v;
}

// ---------------- W pack: [H][512][DH] -> Bt [H*DH][512], LDS-tiled transpose ----------------
__global__ __launch_bounds__(256) void pack_wt(const float* __restrict__ Wq,
                                               const float* __restrict__ Wk,
                                               const float* __restrict__ Wv,
                                               bf16* __restrict__ oq, bf16* __restrict__ ok,
                                               bf16* __restrict__ ov) {
  int z = blockIdx.z;
  const float* W = (z == 0) ? Wq : (z == 1) ? Wk : Wv;
  bf16* out = (z == 0) ? oq : (z == 1) ? ok : ov;
  int DH = (z == 2) ? 256 : 128;
  int nt = DH >> 6;
  int y = blockIdx.y;
  if (y >= 4 * nt) return;
  int h = y / nt, tt = y - h * nt;
  int d0 = blockIdx.x * 64, t0 = tt * 64;
  __shared__ float tile[64][65];
  for (int i = threadIdx.x; i < 4096; i += 256) {
    int r = i >> 6, c = i & 63;
    tile[r][c] = W[((size_t)h * 512 + d0 + r) * DH + t0 + c];
  }
  __syncthreads();
  for (int i = threadIdx.x; i < 4096; i += 256) {
    int t = i >> 6, d = i & 63;
    out[((size_t)(h * DH + t0 + t)) * 512 + d0 + d] = to_bf16(tile[d][t]);
  }
}

// ---------------- 128xBN GEMM body: C[M][N] = A[M][K] * Bt[N][K]^T ----------------
// m97 structure: global_load_lds staging with pre-swizzled source (granule G of row r
// stored at position G^(r&7) -> conflict-free ds_read_b128 fragment reads), BK=64,
// 4 waves in a 2x2 grid of (64 x BN/2) outputs, 2 barriers per K-step.
template <int BN, typename OutT>
__device__ __forceinline__ void gemm_body(const bf16* __restrict__ A,
                                          const bf16* __restrict__ Bt,
                                          OutT* __restrict__ C, int N, int K,
                                          int m0, int n0, bf16* As, bf16* Bs) {
  constexpr int WN = BN / 2;    // per-wave n extent
  constexpr int JN = WN / 16;   // B-fragment count per wave
  int tid = threadIdx.x;
  int lane = tid & 63, w = tid >> 6;
  int quad = lane >> 4, l16 = lane & 15;
  int wm = (w >> 1) * 64, wn = (w & 1) * WN;
  int srow = lane >> 3;            // row-within-8-group staged by this lane
  int sG = (lane & 7) ^ srow;      // source granule for stored position lane&7

  f32x4 acc[4][JN] = {};
  for (int k0 = 0; k0 < K; k0 += 64) {
#pragma unroll
    for (int j = 0; j < 4; j++) {
      int rg = 4 * j + w;          // 8-row group
      dma16(&A[(long)(m0 + rg * 8 + srow) * K + k0 + sG * 8], &As[rg * 512]);
      if (j < BN / 32)
        dma16(&Bt[(long)(n0 + rg * 8 + srow) * K + k0 + sG * 8], &Bs[rg * 512]);
    }
    __syncthreads();
#pragma unroll
    for (int kk = 0; kk < 2; kk++) {
      bf16x8 af[4], bfr[JN];
#pragma unroll
      for (int i = 0; i < 4; i++) {
        int r = wm + i * 16 + l16;
        af[i] = *(const bf16x8*)&As[r * 64 + (((kk * 4 + quad) ^ r) & 7) * 8];
      }
#pragma unroll
      for (int j = 0; j < JN; j++) {
        int r = wn + j * 16 + l16;
        bfr[j] = *(const bf16x8*)&Bs[r * 64 + (((kk * 4 + quad) ^ r) & 7) * 8];
      }
#pragma unroll
      for (int i = 0; i < 4; i++)
#pragma unroll
        for (int j = 0; j < JN; j++)
          acc[i][j] = __builtin_amdgcn_mfma_f32_16x16x32_bf16(af[i], bfr[j], acc[i][j], 0, 0, 0);
    }
    __syncthreads();
  }
#pragma unroll
  for (int i = 0; i < 4; i++)
#pragma unroll
    for (int j = 0; j < JN; j++)
#pragma unroll
      for (int r = 0; r < 4; r++) {
        long row = m0 + wm + i * 16 + quad * 4 + r;
        long col = n0 + wn + j * 16 + l16;
        if constexpr (std::is_same<OutT, bf16>::value)
          C[row * N + col] = to_bf16(acc[i][j][r]);
        else
          C[row * N + col] = acc[i][j][r];
      }
}

// merged q/k/v projections: z picks contiguous slices of inputs/weights/outputs
__global__ __launch_bounds__(256) void proj_gemm(const bf16* __restrict__ QKVb,
                                                 const bf16* __restrict__ Wt,
                                                 bf16* __restrict__ Cout) {
  int z = blockIdx.z;
  int N = (z == 2) ? 1024 : 512;
  if ((int)(blockIdx.y * 128) >= N) return;   // block-uniform early-out
  __shared__ __align__(16) bf16 As[128 * 64];
  __shared__ __align__(16) bf16 Bs[128 * 64];
  const bf16* A = QKVb + (size_t)z * 2097152;
  const bf16* Bt = Wt + ((z == 2) ? (size_t)524288 : (size_t)z * 262144);
  bf16* C = Cout + (size_t)z * 2097152;
  gemm_body<128, bf16>(A, Bt, C, N, 512, blockIdx.x * 128, blockIdx.y * 128, As, Bs);
}

// output projection: 128x64 tiles -> 256 blocks (fill all CUs)
__global__ __launch_bounds__(256) void out_gemm(const bf16* __restrict__ xin,
                                                const bf16* __restrict__ Wob,
                                                float* __restrict__ outp) {
  __shared__ __align__(16) bf16 As[128 * 64];
  __shared__ __align__(16) bf16 Bs[64 * 64];
  gemm_body<64, float>(xin, Wob, outp, 512, 1024, blockIdx.x * 128, blockIdx.y * 64, As, Bs);
}

// ---------------- transpose (R x C) -> (C x R): per-thread 8x8 register transpose ----------------
__global__ __launch_bounds__(256) void transpose_bf16(const bf16* __restrict__ in,
                                                      bf16* __restrict__ out, int R, int Cc) {
  long T = (long)blockIdx.x * 256 + threadIdx.x;
  long nrb = (long)(R >> 3);
  long rb = T % nrb;                 // lane-contiguous -> coalesced stores
  long cb = T / nrb;
  union { bf16 h[8]; bf16x8 v; } a[8], b[8];
#pragma unroll
  for (int i = 0; i < 8; i++) a[i].v = *(const bf16x8*)&in[(rb * 8 + i) * Cc + cb * 8];
#pragma unroll
  for (int j = 0; j < 8; j++) {
#pragma unroll
    for (int i = 0; i < 8; i++) b[j].h[i] = a[i].h[j];
    *(bf16x8*)&out[(cb * 8 + j) * R + rb * 8] = b[j].v;
  }
}

// ---------------- fused attention ----------------
// qb,kb: [N][512]; vT: [1024][N]; x: [N][1024]
// 512 threads = 8 waves; 64 queries/block; 64-key tiles.
// R2: (1) XCD-aware (head,q0) mapping: xcd=bid&7 -> head=xcd&3, so each XCD's L2 holds
//     exactly one head's K+V slice (3 MB < 4 MB) -> staging served by L2, not L3.
// (2) triple-buffered kt/vt (147 KB LDS) + 2-deep prefetch (vmcnt(6) with 12 in
//     flight) + barrier C removed: buffer staged at iter t (tile t+2) was last read at
//     t-1, and barrier A(t) already orders all waves past PV(t-1) -> 2 barriers/tile.
// (3) s_setprio(1) around MFMA clusters (T5).
__global__ __launch_bounds__(512, 2) void attn(const bf16* __restrict__ qb,
                                               const bf16* __restrict__ kb,
                                               const bf16* __restrict__ vT,
                                               bf16* __restrict__ x) {
  __shared__ __align__(16) bf16 kt[3][64 * 128];   // [key][dk] swizzled, 3x16 KB
  __shared__ __align__(16) bf16 vt[3][256 * 64];   // [dv][key] swizzled, 3x32 KB
  __shared__ __align__(16) bf16 pt[64 * 72];       // [q][key], padded
  __shared__ float Lrow[64];

  const int bid = blockIdx.x;
  const int xcd = bid & 7;
  const int head = xcd & 3;                        // one head per XCD (x2)
  const int q0 = ((xcd >> 2) * 32 + (bid >> 3)) * 64;
  const int tid = threadIdx.x;
  const int lane = tid & 63, w = tid >> 6;
  const int quad = lane >> 4, l16 = lane & 15;
  const int cd = w & 3;   // S: key-col tile; PV: dv group
  const int g = w >> 2;   // q half

  // all-ones B-fragment: B[n][k] = (n==0) -> D[q][0] = sum_k P[q][k]
  bf16x8 onesf;
  {
    union { bf16 h[8]; bf16x8 v; } u;
    bf16 one = to_bf16(1.0f), zero = to_bf16(0.0f);
#pragma unroll
    for (int j = 0; j < 8; j++) u.h[j] = (l16 == 0) ? one : zero;
    onesf = u.v;
  }

  // preload q fragments (A-layout: m=l16, k=quad*8+j)
  bf16x8 qf[2][4];
#pragma unroll
  for (int i = 0; i < 2; i++) {
    const bf16* qrow = &qb[(size_t)(q0 + g * 32 + i * 16 + l16) * 512 + head * 128];
#pragma unroll
    for (int kk = 0; kk < 4; kk++) qf[i][kk] = *(const bf16x8*)&qrow[kk * 32 + quad * 8];
  }

  f32x4 oacc[2][4] = {};
  f32x4 oL[2] = {};
  const float scale = 1.0f / 64.0f;  // 1/sqrt(4096)

  // stage one key-tile into buffer b: 6 DMA instrs per wave (2 kt + 4 vt)
  auto stage = [&](int b, int key0) {
#pragma unroll
    for (int t2 = 0; t2 < 2; t2++) {
      int j = 2 * w + t2;
      int r = 4 * j + (lane >> 4);            // key row 0..63
      int p = lane & 15;                      // stored granule position
      int G = (p & 8) | ((p ^ r) & 7);        // source granule (inverse swizzle)
      dma16(&kb[(size_t)(key0 + r) * 512 + head * 128 + G * 8], &kt[b][j * 512]);
    }
#pragma unroll
    for (int t2 = 0; t2 < 4; t2++) {
      int j = 4 * w + t2;
      int r = 8 * j + (lane >> 3);            // dv row 0..255
      int p = lane & 7;
      int G = (p ^ r) & 7;
      dma16(&vT[(size_t)(head * 256 + r) * 4096 + key0 + G * 8], &vt[b][j * 512]);
    }
  };

  stage(0, 0);
  stage(1, 64);
  asm volatile("" ::: "memory");
  int bc = 0;  // buffer of tile t (= t % 3)

  for (int t = 0; t < 64; ++t) {
    // ---- wait (counted) for tile t; tile t+1 stays in flight ----
    if (t < 63) asm volatile("s_waitcnt vmcnt(6)" ::: "memory");
    else        asm volatile("s_waitcnt vmcnt(0)" ::: "memory");
    __builtin_amdgcn_s_barrier();          // barrier A: all waves' tile-t DMA landed
    asm volatile("" ::: "memory");

    // ---- issue tile t+2 DMA into buffer (t+2)%3 (last read at t-1, ordered by A) ----
    if (t < 62) {
      int bs = bc + 2; if (bs >= 3) bs -= 3;
      stage(bs, (t + 2) * 64);
    }

    // ---- S = q @ k^T : this wave: q rows g*32..+31, key col cd ----
    const bf16* ktc = kt[bc];
    f32x4 sacc[2] = {};
    __builtin_amdgcn_s_setprio(1);
#pragma unroll
    for (int kk = 0; kk < 4; kk++) {
      int R = cd * 16 + l16;
      int G = kk * 4 + quad;
      bf16x8 kf = *(const bf16x8*)&ktc[R * 128 + (((G ^ R) & 7) | (G & 8)) * 8];
      sacc[0] = __builtin_amdgcn_mfma_f32_16x16x32_bf16(qf[0][kk], kf, sacc[0], 0, 0, 0);
      sacc[1] = __builtin_amdgcn_mfma_f32_16x16x32_bf16(qf[1][kk], kf, sacc[1], 0, 0, 0);
    }
    __builtin_amdgcn_s_setprio(0);
#pragma unroll
    for (int i = 0; i < 2; i++)
#pragma unroll
      for (int r = 0; r < 4; r++)
        pt[(g * 32 + i * 16 + quad * 4 + r) * 72 + cd * 16 + l16] =
            to_bf16(__expf(sacc[i][r] * scale));
    asm volatile("s_waitcnt lgkmcnt(0)" ::: "memory");   // own pt writes visible
    __builtin_amdgcn_s_barrier();          // barrier B: pt ready
    asm volatile("" ::: "memory");

    // ---- O += P @ v : this wave: q rows g*32..+31, dv cols cd*64..+63 ----
    const bf16* vtc = vt[bc];
    __builtin_amdgcn_s_setprio(1);
#pragma unroll
    for (int kk = 0; kk < 2; kk++) {
      bf16x8 pf[2];
#pragma unroll
      for (int i = 0; i < 2; i++)
        pf[i] = *(const bf16x8*)&pt[(g * 32 + i * 16 + l16) * 72 + kk * 32 + quad * 8];
#pragma unroll
      for (int c = 0; c < 4; c++) {
        int R = cd * 64 + c * 16 + l16;
        int G = kk * 4 + quad;
        bf16x8 vf = *(const bf16x8*)&vtc[R * 64 + ((G ^ R) & 7) * 8];
#pragma unroll
        for (int i = 0; i < 2; i++)
          oacc[i][c] = __builtin_amdgcn_mfma_f32_16x16x32_bf16(pf[i], vf, oacc[i][c], 0, 0, 0);
      }
      if (cd == 3) {  // wave-uniform: L column
#pragma unroll
        for (int i = 0; i < 2; i++)
          oL[i] = __builtin_amdgcn_mfma_f32_16x16x32_bf16(pf[i], onesf, oL[i], 0, 0, 0);
      }
    }
    __builtin_amdgcn_s_setprio(0);
    asm volatile("" ::: "memory");         // next iter's barrier A orders buffer reuse
    bc = (bc + 1 == 3) ? 0 : bc + 1;
  }

  // L at lanes l16==0 of cd==3 waves (C-layout col 0)
  if (cd == 3 && l16 == 0) {
#pragma unroll
    for (int i = 0; i < 2; i++)
#pragma unroll
      for (int r = 0; r < 4; r++) Lrow[g * 32 + i * 16 + quad * 4 + r] = oL[i][r];
  }
  __syncthreads();

  // normalize + write x[n][head*256 + dv]
#pragma unroll
  for (int i = 0; i < 2; i++)
#pragma unroll
    for (int c = 0; c < 4; c++)
#pragma unroll
      for (int r = 0; r < 4; r++) {
        int row = g * 32 + i * 16 + quad * 4 + r;
        float v = oacc[i][c][r] / Lrow[row];
        x[(size_t)(q0 + row) * 1024 + head * 256 + cd * 64 + c * 16 + l16] = to_bf16(v);
      }
}

// ---------------- launch ----------------
extern "C" void kernel_launch(void* const* d_in, const int* in_sizes, int n_in,
                              void* d_out, int out_size, void* d_ws, size_t ws_size,
                              hipStream_t stream) {
  const float* Q  = (const float*)d_in[0];
  const float* Km = (const float*)d_in[1];
  const float* V  = (const float*)d_in[2];
  const float* Wq = (const float*)d_in[3];
  const float* Wk = (const float*)d_in[4];
  const float* Wv = (const float*)d_in[5];
  const float* Wo = (const float*)d_in[6];
  float* out = (float*)d_out;

  bf16* ws  = (bf16*)d_ws;
  bf16* Qb  = ws;                 // 4096x512   (Qb,Kb,Vb contiguous)
  bf16* Kb  = Qb + 2097152;
  bf16* Vb  = Kb + 2097152;
  bf16* Wqt = Vb + 2097152;       // 512x512  (Wqt,Wkt,Wvt contiguous)
  bf16* Wkt = Wqt + 262144;
  bf16* Wvt = Wkt + 262144;       // 1024x512 (Bt)
  bf16* Wob = Wvt + 524288;       // 512x1024 (Bt = Wo as-is)
  bf16* qb  = Wob + 524288;       // 4096x512   (qb,kb,vb contiguous)
  bf16* kb  = qb + 2097152;
  bf16* vb  = kb + 2097152;       // 4096x1024
  bf16* vT  = vb + 4194304;       // 1024x4096
  bf16* x   = vT + 4194304;       // 4096x1024

  convert_all<<<3328, 256, 0, stream>>>(Q, Km, V, Wo, Qb, Kb, Vb, Wob);
  pack_wt<<<dim3(8, 16, 3), 256, 0, stream>>>(Wq, Wk, Wv, Wqt, Wkt, Wvt);

  proj_gemm<<<dim3(32, 8, 3), 256, 0, stream>>>(Qb, Wqt, qb);
  transpose_bf16<<<256, 256, 0, stream>>>(vb, vT, 4096, 1024);

  attn<<<256, 512, 0, stream>>>(qb, kb, vT, x);

  out_gemm<<<dim3(32, 8), 256, 0, stream>>>(x, Wob, out);
}

// Round 3
// 214.152 us; speedup vs baseline: 1.1662x; 1.0311x over previous
//
#include <hip/hip_runtime.h>
#include <hip/hip_bf16.h>
#include <type_traits>

typedef __hip_bfloat16 bf16;
typedef __attribute__((ext_vector_type(8))) short bf16x8;
typedef __attribute__((ext_vector_type(4))) float f32x4;

#define N_LOC 4096

__device__ __forceinline__ bf16 to_bf16(float f) { return __float2bfloat16(f); }

// async global->LDS DMA, 16B per lane; LDS dest = wave-uniform base + lane*16
__device__ __forceinline__ void dma16(const bf16* g, bf16* l) {
  __builtin_amdgcn_global_load_lds((const __attribute__((address_space(1))) unsigned int*)g,
                                   (__attribute__((address_space(3))) unsigned int*)l, 16, 0, 0);
}

// ---------------- prep: fused {f32->bf16 convert of Q,K,V,Wo} + {W transpose-pack} ----------------
__global__ __launch_bounds__(256) void prep(const float* __restrict__ Q, const float* __restrict__ K,
                                            const float* __restrict__ V, const float* __restrict__ Wo,
                                            bf16* __restrict__ Qb, bf16* __restrict__ Kb,
                                            bf16* __restrict__ Vb, bf16* __restrict__ Wob,
                                            const float* __restrict__ Wq, const float* __restrict__ Wk,
                                            const float* __restrict__ Wv,
                                            bf16* __restrict__ oq, bf16* __restrict__ ok,
                                            bf16* __restrict__ ov) {
  __shared__ float tile[64][65];
  if (blockIdx.x < 3328) {
    long i = ((long)blockIdx.x * 256 + threadIdx.x) * 8;
    const float* src;
    bf16* dst;
    long off;
    if (i < 2097152)      { src = Q;  dst = Qb;  off = i; }
    else if (i < 4194304) { src = K;  dst = Kb;  off = i - 2097152; }
    else if (i < 6291456) { src = V;  dst = Vb;  off = i - 4194304; }
    else                  { src = Wo; dst = Wob; off = i - 6291456; }
    float4 a = *(const float4*)&src[off];
    float4 b = *(const float4*)&src[off + 4];
    union { bf16 h[8]; bf16x8 v; } u;
    u.h[0] = to_bf16(a.x); u.h[1] = to_bf16(a.y); u.h[2] = to_bf16(a.z); u.h[3] = to_bf16(a.w);
    u.h[4] = to_bf16(b.x); u.h[5] = to_bf16(b.y); u.h[6] = to_bf16(b.z); u.h[7] = to_bf16(b.w);
    *(bf16x8*)&dst[off] = u.v;
  } else {
    int pid = blockIdx.x - 3328;            // 0..383  (old dims: x 8, y 16, z 3)
    int z = pid >> 7;
    int rem = pid & 127;
    int xx = rem & 7, y = rem >> 3;
    const float* W = (z == 0) ? Wq : (z == 1) ? Wk : Wv;
    bf16* out = (z == 0) ? oq : (z == 1) ? ok : ov;
    int DH = (z == 2) ? 256 : 128;
    int nt = DH >> 6;
    if (y >= 4 * nt) return;
    int h = y / nt, tt = y - h * nt;
    int d0 = xx * 64, t0 = tt * 64;
    for (int i = threadIdx.x; i < 4096; i += 256) {
      int r = i >> 6, c = i & 63;
      tile[r][c] = W[((size_t)h * 512 + d0 + r) * DH + t0 + c];
    }
    __syncthreads();
    for (int i = threadIdx.x; i < 4096; i += 256) {
      int t = i >> 6, d = i & 63;
      out[((size_t)(h * DH + t0 + t)) * 512 + d0 + d] = to_bf16(tile[d][t]);
    }
  }
}

// ---------------- 128xBN GEMM body, double-buffered counted-vmcnt staging ----------------
// MODE 0: C bf16 [M][N]; MODE 1: C f32 [M][N]; MODE 2: C bf16 TRANSPOSED (vT[col][row], ld 4096)
// Staging: global_load_lds with pre-swizzled source (granule G of row r stored at pos G^(r&7))
// -> conflict-free ds_read_b128 frags. Stage k+1 issued before waiting (vmcnt counted) on k.
template <int BN, int MODE, typename OutT>
__device__ __forceinline__ void gemm_body(const bf16* __restrict__ A, const bf16* __restrict__ Bt,
                                          OutT* __restrict__ C, int N, int K, int m0, int n0,
                                          bf16* sm) {
  constexpr int WN = BN / 2, JN = WN / 16, NB = BN / 32;
  int tid = threadIdx.x, lane = tid & 63, w = tid >> 6;
  int quad = lane >> 4, l16 = lane & 15;
  int wm = (w >> 1) * 64, wn = (w & 1) * WN;
  int srow = lane >> 3;            // row-within-8-group staged by this lane
  int sG = (lane & 7) ^ srow;      // source granule for stored position lane&7

  bf16* Asb[2] = { sm, sm + 8192 };
  bf16* Bsb[2] = { sm + 16384, sm + 16384 + BN * 64 };

  const bf16* ga[4];
  const bf16* gb[NB];
#pragma unroll
  for (int j = 0; j < 4; j++) ga[j] = A + (long)(m0 + (4 * j + w) * 8 + srow) * K + sG * 8;
#pragma unroll
  for (int j = 0; j < NB; j++) gb[j] = Bt + (long)(n0 + (4 * j + w) * 8 + srow) * K + sG * 8;

  auto stage = [&](int b) {
#pragma unroll
    for (int j = 0; j < 4; j++) { dma16(ga[j], &Asb[b][(4 * j + w) * 512]); ga[j] += 64; }
#pragma unroll
    for (int j = 0; j < NB; j++) { dma16(gb[j], &Bsb[b][(4 * j + w) * 512]); gb[j] += 64; }
  };

  f32x4 acc[4][JN] = {};
  stage(0);
  asm volatile("" ::: "memory");
  int cur = 0;
  const int NK = K >> 6;
  for (int s = 0; s < NK; ++s) {
    if (s + 1 < NK) {
      stage(cur ^ 1);
      if constexpr (NB == 4) asm volatile("s_waitcnt vmcnt(8)" ::: "memory");
      else                   asm volatile("s_waitcnt vmcnt(6)" ::: "memory");
    } else {
      asm volatile("s_waitcnt vmcnt(0)" ::: "memory");
    }
    __builtin_amdgcn_s_barrier();      // tile s landed for all waves
    asm volatile("" ::: "memory");
    const bf16* Ac = Asb[cur];
    const bf16* Bc = Bsb[cur];
#pragma unroll
    for (int kk = 0; kk < 2; kk++) {
      bf16x8 af[4], bfr[JN];
#pragma unroll
      for (int i = 0; i < 4; i++) {
        int r = wm + i * 16 + l16;
        af[i] = *(const bf16x8*)&Ac[r * 64 + (((kk * 4 + quad) ^ r) & 7) * 8];
      }
#pragma unroll
      for (int j = 0; j < JN; j++) {
        int r = wn + j * 16 + l16;
        bfr[j] = *(const bf16x8*)&Bc[r * 64 + (((kk * 4 + quad) ^ r) & 7) * 8];
      }
#pragma unroll
      for (int i = 0; i < 4; i++)
#pragma unroll
        for (int j = 0; j < JN; j++)
          acc[i][j] = __builtin_amdgcn_mfma_f32_16x16x32_bf16(af[i], bfr[j], acc[i][j], 0, 0, 0);
    }
    asm volatile("" ::: "memory");
    __builtin_amdgcn_s_barrier();      // buf cur free for next stage's overwrite
    asm volatile("" ::: "memory");
    cur ^= 1;
  }

  if constexpr (MODE == 2) {
    // LDS-transposed epilogue: acc -> tile[n_local][m_local] (padded), then coalesced 16B
    // stores to vT[(n0+nl)*4096 + m0 + ml]. sm is free after the loop's closing barrier.
    bf16* tp = sm;  // [128][136] bf16 = 34.8 KB (sm is 64 KB)
#pragma unroll
    for (int i = 0; i < 4; i++)
#pragma unroll
      for (int j = 0; j < JN; j++)
#pragma unroll
        for (int r = 0; r < 4; r++)
          tp[(wn + j * 16 + l16) * 136 + wm + i * 16 + quad * 4 + r] = to_bf16(acc[i][j][r]);
    __syncthreads();
#pragma unroll
    for (int it = 0; it < 8; ++it) {
      int idx = it * 256 + tid;
      int rown = idx >> 4, c8 = (idx & 15) * 8;
      *(bf16x8*)&C[(size_t)(n0 + rown) * 4096 + m0 + c8] = *(const bf16x8*)&tp[rown * 136 + c8];
    }
  } else {
#pragma unroll
    for (int i = 0; i < 4; i++)
#pragma unroll
      for (int j = 0; j < JN; j++)
#pragma unroll
        for (int r = 0; r < 4; r++) {
          long row = m0 + wm + i * 16 + quad * 4 + r;
          long col = n0 + wn + j * 16 + l16;
          if constexpr (MODE == 0)
            C[row * N + col] = to_bf16(acc[i][j][r]);
          else
            C[row * N + col] = acc[i][j][r];
        }
  }
}

// merged q/k/v projections, exact 512-block grid; z==2 writes vT directly (transposed epilogue)
__global__ __launch_bounds__(256) void proj_gemm(const bf16* __restrict__ QKVb,
                                                 const bf16* __restrict__ Wt,
                                                 bf16* __restrict__ qkout,
                                                 bf16* __restrict__ vTout) {
  __shared__ __align__(16) bf16 sm[4 * 128 * 64];   // 64 KB
  int bid = blockIdx.x;
  if (bid < 256) {
    int z = bid >> 7;                 // 0:q 1:k
    int t = bid & 127;
    int m0 = (t & 31) * 128, n0 = (t >> 5) * 128;
    gemm_body<128, 0, bf16>(QKVb + (size_t)z * 2097152, Wt + (size_t)z * 262144,
                            qkout + (size_t)z * 2097152, 512, 512, m0, n0, sm);
  } else {
    int t = bid - 256;                // 0..255 -> v projection, 4096x1024
    int m0 = (t & 31) * 128, n0 = (t >> 5) * 128;
    gemm_body<128, 2, bf16>(QKVb + (size_t)2 * 2097152, Wt + (size_t)2 * 262144,
                            vTout, 1024, 512, m0, n0, sm);
  }
}

// output projection: 128x64 tiles -> 256 blocks
__global__ __launch_bounds__(256) void out_gemm(const bf16* __restrict__ xin,
                                                const bf16* __restrict__ Wob,
                                                float* __restrict__ outp) {
  __shared__ __align__(16) bf16 sm[2 * 128 * 64 + 2 * 64 * 64];   // 48 KB
  gemm_body<64, 1, float>(xin, Wob, outp, 512, 1024, blockIdx.x * 128, blockIdx.y * 64, sm);
}

// ---------------- fused attention ----------------
// qb,kb: [N][512]; vT: [1024][N]; x: [N][1024]
// R3: dv-split -> 512 blocks (2 blocks/CU, 16 waves/CU): block = (head, q0, dvh) owns
// 64 q-rows x 128 dv-cols; S (cheap) computed redundantly per dv-half. Double-buffered
// kt (16 KB) + vt-half (16 KB), R1-proven 3-barrier counted-vmcnt pattern, no setprio.
// DMA sources are incremented pointers (no per-tile 64-bit addr recompute).
__global__ __launch_bounds__(512, 4) void attn(const bf16* __restrict__ qb,
                                               const bf16* __restrict__ kb,
                                               const bf16* __restrict__ vT,
                                               bf16* __restrict__ x) {
  __shared__ __align__(16) bf16 kt[2][64 * 128];   // [key][dk] swizzled, 2x16 KB
  __shared__ __align__(16) bf16 vt[2][128 * 64];   // [dv-half][key] swizzled, 2x16 KB
  __shared__ __align__(16) bf16 pt[64 * 72];       // [q][key], padded
  __shared__ float Lrow[64];

  const int bid = blockIdx.x;                      // 512 blocks
  const int xcd = bid & 7;
  const int head = xcd & 3;                        // one (head,dvh) pair per XCD
  const int dvh = xcd >> 2;                        // dv half 0..1
  const int q0 = (bid >> 3) * 64;                  // 0..4032
  const int tid = threadIdx.x;
  const int lane = tid & 63, w = tid >> 6;
  const int quad = lane >> 4, l16 = lane & 15;
  const int cd = w & 3;   // S: 16-key col tile; PV: 32-dv group
  const int g = w >> 2;   // q half

  // all-ones B-fragment: B[n][k] = (n==0) -> D[q][0] = sum_k P[q][k]
  bf16x8 onesf;
  {
    union { bf16 h[8]; bf16x8 v; } u;
    bf16 one = to_bf16(1.0f), zero = to_bf16(0.0f);
#pragma unroll
    for (int j = 0; j < 8; j++) u.h[j] = (l16 == 0) ? one : zero;
    onesf = u.v;
  }

  // preload q fragments (A-layout: m=l16, k=quad*8+j)
  bf16x8 qf[2][4];
#pragma unroll
  for (int i = 0; i < 2; i++) {
    const bf16* qrow = &qb[(size_t)(q0 + g * 32 + i * 16 + l16) * 512 + head * 128];
#pragma unroll
    for (int kk = 0; kk < 4; kk++) qf[i][kk] = *(const bf16x8*)&qrow[kk * 32 + quad * 8];
  }

  f32x4 oacc[2][2] = {};
  f32x4 oL[2] = {};
  const float scale = 1.0f / 64.0f;  // 1/sqrt(4096)

  // DMA source pointers (advance per tile). kt: 16 j-groups (4 rows x 128 dk each);
  // vt: 16 j-groups (8 rows x 64 keys each). j = 2w+t2.
  const int j0 = 2 * w, j1 = 2 * w + 1;
  const bf16 *kp0, *kp1, *vp0, *vp1;
  {
    int r0 = 4 * j0 + (lane >> 4), r1 = 4 * j1 + (lane >> 4);
    int p = lane & 15;
    int G0 = (p & 8) | ((p ^ r0) & 7), G1 = (p & 8) | ((p ^ r1) & 7);
    kp0 = kb + (size_t)r0 * 512 + head * 128 + G0 * 8;
    kp1 = kb + (size_t)r1 * 512 + head * 128 + G1 * 8;
  }
  {
    int r0 = 8 * j0 + (lane >> 3), r1 = 8 * j1 + (lane >> 3);
    int p = lane & 7;
    int G0 = (p ^ r0) & 7, G1 = (p ^ r1) & 7;
    vp0 = vT + (size_t)(head * 256 + dvh * 128 + r0) * 4096 + G0 * 8;
    vp1 = vT + (size_t)(head * 256 + dvh * 128 + r1) * 4096 + G1 * 8;
  }

#define STAGE(b)                                        \
  do {                                                  \
    dma16(kp0, &kt[b][j0 * 512]);                       \
    dma16(kp1, &kt[b][j1 * 512]);                       \
    dma16(vp0, &vt[b][j0 * 512]);                       \
    dma16(vp1, &vt[b][j1 * 512]);                       \
    kp0 += 64 * 512; kp1 += 64 * 512;                   \
    vp0 += 64; vp1 += 64;                               \
  } while (0)

  STAGE(0);
  asm volatile("" ::: "memory");
  int cur = 0;

  for (int t = 0; t < 64; ++t) {
    // issue tile t+1's DMA into the other buffer (its last reads finished before
    // barrier C of iter t-1), then counted-wait for tile t (t+1's 4 stay in flight)
    if (t < 63) {
      STAGE(cur ^ 1);
      asm volatile("s_waitcnt vmcnt(4)" ::: "memory");
    } else {
      asm volatile("s_waitcnt vmcnt(0)" ::: "memory");
    }
    __builtin_amdgcn_s_barrier();          // A: tile t landed for all waves
    asm volatile("" ::: "memory");

    // ---- S = q @ k^T : q rows g*32..+31, key cols cd*16..+15 ----
    const bf16* ktc = kt[cur];
    f32x4 sacc[2] = {};
#pragma unroll
    for (int kk = 0; kk < 4; kk++) {
      int R = cd * 16 + l16;
      int G = kk * 4 + quad;
      bf16x8 kf = *(const bf16x8*)&ktc[R * 128 + (((G ^ R) & 7) | (G & 8)) * 8];
      sacc[0] = __builtin_amdgcn_mfma_f32_16x16x32_bf16(qf[0][kk], kf, sacc[0], 0, 0, 0);
      sacc[1] = __builtin_amdgcn_mfma_f32_16x16x32_bf16(qf[1][kk], kf, sacc[1], 0, 0, 0);
    }
#pragma unroll
    for (int i = 0; i < 2; i++)
#pragma unroll
      for (int r = 0; r < 4; r++)
        pt[(g * 32 + i * 16 + quad * 4 + r) * 72 + cd * 16 + l16] =
            to_bf16(__expf(sacc[i][r] * scale));
    asm volatile("s_waitcnt lgkmcnt(0)" ::: "memory");   // own pt writes visible
    __builtin_amdgcn_s_barrier();          // B: pt ready
    asm volatile("" ::: "memory");

    // ---- O += P @ v : q rows g*32..+31, dv cols cd*32..+31 (of this half) ----
    const bf16* vtc = vt[cur];
#pragma unroll
    for (int kk = 0; kk < 2; kk++) {
      bf16x8 pf[2];
#pragma unroll
      for (int i = 0; i < 2; i++)
        pf[i] = *(const bf16x8*)&pt[(g * 32 + i * 16 + l16) * 72 + kk * 32 + quad * 8];
#pragma unroll
      for (int c = 0; c < 2; c++) {
        int R = cd * 32 + c * 16 + l16;
        int G = kk * 4 + quad;
        bf16x8 vf = *(const bf16x8*)&vtc[R * 64 + ((G ^ R) & 7) * 8];
#pragma unroll
        for (int i = 0; i < 2; i++)
          oacc[i][c] = __builtin_amdgcn_mfma_f32_16x16x32_bf16(pf[i], vf, oacc[i][c], 0, 0, 0);
      }
      if (cd == 3) {  // wave-uniform: L column (full P tile available in pt)
#pragma unroll
        for (int i = 0; i < 2; i++)
          oL[i] = __builtin_amdgcn_mfma_f32_16x16x32_bf16(pf[i], onesf, oL[i], 0, 0, 0);
      }
    }
    asm volatile("" ::: "memory");
    __builtin_amdgcn_s_barrier();          // C: all reads of buf cur done
    asm volatile("" ::: "memory");
    cur ^= 1;
  }
#undef STAGE

  // L at lanes l16==0 of cd==3 waves (C-layout col 0)
  if (cd == 3 && l16 == 0) {
#pragma unroll
    for (int i = 0; i < 2; i++)
#pragma unroll
      for (int r = 0; r < 4; r++) Lrow[g * 32 + i * 16 + quad * 4 + r] = oL[i][r];
  }
  __syncthreads();

  // normalize + write x[n][head*256 + dvh*128 + dv]
#pragma unroll
  for (int i = 0; i < 2; i++)
#pragma unroll
    for (int c = 0; c < 2; c++)
#pragma unroll
      for (int r = 0; r < 4; r++) {
        int row = g * 32 + i * 16 + quad * 4 + r;
        float v = oacc[i][c][r] / Lrow[row];
        x[(size_t)(q0 + row) * 1024 + head * 256 + dvh * 128 + cd * 32 + c * 16 + l16] =
            to_bf16(v);
      }
}

// ---------------- launch ----------------
extern "C" void kernel_launch(void* const* d_in, const int* in_sizes, int n_in,
                              void* d_out, int out_size, void* d_ws, size_t ws_size,
                              hipStream_t stream) {
  const float* Q  = (const float*)d_in[0];
  const float* Km = (const float*)d_in[1];
  const float* V  = (const float*)d_in[2];
  const float* Wq = (const float*)d_in[3];
  const float* Wk = (const float*)d_in[4];
  const float* Wv = (const float*)d_in[5];
  const float* Wo = (const float*)d_in[6];
  float* out = (float*)d_out;

  bf16* ws  = (bf16*)d_ws;
  bf16* Qb  = ws;                 // 4096x512   (Qb,Kb,Vb contiguous)
  bf16* Kb  = Qb + 2097152;
  bf16* Vb  = Kb + 2097152;
  bf16* Wqt = Vb + 2097152;       // 512x512  (Wqt,Wkt,Wvt contiguous)
  bf16* Wkt = Wqt + 262144;
  bf16* Wvt = Wkt + 262144;       // 1024x512 (Bt)
  bf16* Wob = Wvt + 524288;       // 512x1024 (Bt = Wo as-is)
  bf16* qb  = Wob + 524288;       // 4096x512   (qb,kb contiguous)
  bf16* kb  = qb + 2097152;
  bf16* vT  = kb + 2097152;       // 1024x4096  (written directly by proj z==2)
  bf16* x   = vT + 4194304;       // 4096x1024

  prep<<<3712, 256, 0, stream>>>(Q, Km, V, Wo, Qb, Kb, Vb, Wob, Wq, Wk, Wv, Wqt, Wkt, Wvt);

  proj_gemm<<<512, 256, 0, stream>>>(Qb, Wqt, qb, vT);

  attn<<<512, 512, 0, stream>>>(qb, kb, vT, x);

  out_gemm<<<dim3(32, 8), 256, 0, stream>>>(x, Wob, out);
}